// Round 11
// baseline (511.205 us; speedup 1.0000x reference)
//
#include <hip/hip_runtime.h>
#include <hip/hip_bf16.h>

#define NN 50000
#define NE 800000
#define MPAD 50048   // 391 * 128 (GEMM row padding)
#define BSTR 64      // bucket stride (max in-degree headroom; Poisson(16), ~12 sigma)

typedef __attribute__((ext_vector_type(8))) short short8;
typedef __attribute__((ext_vector_type(4))) float f32x4;
typedef __attribute__((ext_vector_type(4))) unsigned short us4;
typedef __attribute__((ext_vector_type(8))) unsigned short us8;

static __device__ __forceinline__ unsigned short f2bf(float f) {
    union { float f; unsigned int u; } v; v.f = f;
    unsigned int u = v.u;
    return (unsigned short)((u + 0x7FFFu + ((u >> 16) & 1u)) >> 16);  // RNE
}
static __device__ __forceinline__ float bf2f(unsigned short h) {
    union { unsigned int u; float f; } v; v.u = ((unsigned int)h) << 16;
    return v.f;
}

// ---- fused: degree-count + bucket counting-sort (blocks 0..3124) + W transposes ----
// NE = 3125*256 exactly; blocks [3125, 3765) handle the 163840 weight elements.
// bucket is USHORT (src ids < 50000 < 2^16): 6.4 MB, cheap to re-read per column slice.
__global__ void k_degsortW(const int* __restrict__ src, const int* __restrict__ dst,
                           int* __restrict__ degO, int* __restrict__ degI,
                           unsigned short* __restrict__ bucket,
                           const float* __restrict__ W0, const float* __restrict__ W1,
                           const float* __restrict__ W2,
                           unsigned short* __restrict__ W0T, unsigned short* __restrict__ W1T,
                           unsigned short* __restrict__ W2T) {
    int bid = blockIdx.x;
    int t = threadIdx.x;
    if (bid < NE / 256) {
        int e = bid * 256 + t;
        int s = src[e], d = dst[e];
        atomicAdd(&degO[s], 1);
        int p = atomicAdd(&degI[d], 1);
        bucket[d * BSTR + p] = (unsigned short)s;
    } else {
        int i = (bid - NE / 256) * 256 + t;   // 0 .. 163839
        if (i < 65536) {
            int k = i >> 8, c = i & 255;
            W0T[c * 256 + k] = f2bf(W0[i]);
        } else if (i < 131072) {
            int j = i - 65536;
            int k = j >> 8, c = j & 255;
            W1T[c * 256 + k] = f2bf(W1[j]);
        } else {
            int j = i - 131072;
            int k = j >> 7, c = j & 127;
            W2T[c * 256 + k] = f2bf(W2[j]);
        }
    }
}

// ---- prep: norms + layer-0 input cvt, float4-vectorized; 4 rows per block ----
__global__ __launch_bounds__(256) void k_prep(const float* __restrict__ x,
                                              const int* __restrict__ degO,
                                              const int* __restrict__ degI,
                                              float* __restrict__ nS, float* __restrict__ nD,
                                              unsigned short* __restrict__ xb) {
    const int row = blockIdx.x * 4 + (threadIdx.x >> 6);
    const int l = threadIdx.x & 63;
    int o = degO[row];
    float ns = 1.0f / sqrtf((float)(o > 0 ? o : 1));
    if (l == 0) {
        int d = degI[row];
        nS[row] = ns;
        nD[row] = 1.0f / sqrtf((float)(d > 0 ? d : 1));
    }
    f32x4 v = *(const f32x4*)&x[(long)row * 256 + l * 4];
    us4 ob;
#pragma unroll
    for (int k = 0; k < 4; k++) ob[k] = f2bf(v[k] * ns);
    *(us4*)&xb[(long)row * 256 + l * 4] = ob;
}

// ---- gather-aggregate (256-wide bf16), XCD-affine 32-col slices ----
// blockIdx.x % 8 = slice (rides XCD round-robin dispatch): XCD s only gathers from
// cols [s*32, s*32+32) of xb = 3.2 MB -> resident in its private 4 MiB L2.
// Wave per node; 8 edge slots (e=lane>>3) x 8 lanes x us4; edge list in-register
// (ushort bucket, one coalesced 128B read); all __shfl at full exec (R8 lesson).
__global__ __launch_bounds__(256) void k_aggb(const int* __restrict__ degI,
                                              const unsigned short* __restrict__ bucket,
                                              const unsigned short* __restrict__ xb,
                                              const float* __restrict__ nD,
                                              unsigned short* __restrict__ aggb) {
    const int sl = blockIdx.x & 7;
    const int node = (blockIdx.x >> 3) * 4 + (threadIdx.x >> 6);
    const int lane = threadIdx.x & 63;
    const int e = lane >> 3;                      // 8 edge slots
    const int cl = sl * 32 + (lane & 7) * 4;      // ushort col base
    if (node >= NN) {
        if (node < MPAD && e == 0)
            *(us4*)&aggb[(long)node * 256 + cl] = (us4){0, 0, 0, 0};
        return;
    }
    const int deg = degI[node];
    const int bidx = (int)bucket[node * BSTR + lane];  // whole edge list, in-register
    float acc[4] = {0.f, 0.f, 0.f, 0.f};
    int j = 0;
    for (; j + 16 <= deg; j += 16) {              // uniform: full exec; 2 loads in flight
        int s0 = __shfl(bidx, j + e, 64);
        int s1 = __shfl(bidx, j + 8 + e, 64);
        us4 v0 = *(const us4*)&xb[(long)s0 * 256 + cl];
        us4 v1 = *(const us4*)&xb[(long)s1 * 256 + cl];
#pragma unroll
        for (int k = 0; k < 4; k++) acc[k] += bf2f(v0[k]) + bf2f(v1[k]);
    }
    if (j + 8 <= deg) {                           // uniform
        int s0 = __shfl(bidx, j + e, 64);
        us4 v0 = *(const us4*)&xb[(long)s0 * 256 + cl];
#pragma unroll
        for (int k = 0; k < 4; k++) acc[k] += bf2f(v0[k]);
        j += 8;
    }
    if (j < deg) {                                // uniform; j<=56, e<=7 -> j+e<=63
        int s0 = __shfl(bidx, j + e, 64);         // shfl at full exec
        if (e < deg - j) {                        // divergent: gather only
            us4 v0 = *(const us4*)&xb[(long)s0 * 256 + cl];
#pragma unroll
            for (int k = 0; k < 4; k++) acc[k] += bf2f(v0[k]);
        }
    }
#pragma unroll
    for (int k = 0; k < 4; k++) acc[k] += __shfl_xor(acc[k], 8, 64);
#pragma unroll
    for (int k = 0; k < 4; k++) acc[k] += __shfl_xor(acc[k], 16, 64);
#pragma unroll
    for (int k = 0; k < 4; k++) acc[k] += __shfl_xor(acc[k], 32, 64);
    if (e == 0) {
        float nd = nD[node];
        us4 o;
#pragma unroll
        for (int k = 0; k < 4; k++) o[k] = f2bf(acc[k] * nd);
        *(us4*)&aggb[(long)node * 256 + cl] = o;
    }
}

// ---------------- GEMM: A [MPAD][256] bf16, BT [NOUT][256] bf16 (transposed weights) ----
// MODE 0: h = relu(acc + b) -> outF f32 NT-store (row<NN); xbn = f2bf(h*nS) (pad rows -> 0)
// MODE 1: outB = f2bf(acc)  (raw, no bias)
template<int NOUT, int MODE>
__global__ __launch_bounds__(256) void k_gemm(const unsigned short* __restrict__ A,
                                              const unsigned short* __restrict__ BT,
                                              const float* __restrict__ bias,
                                              const float* __restrict__ nS,
                                              float* __restrict__ outF,
                                              unsigned short* __restrict__ xbn,
                                              unsigned short* __restrict__ outB) {
    __shared__ unsigned short As[128][40];
    __shared__ unsigned short Bs[128][36];   // [col][k], staged from BT row-copies
    const int bm = blockIdx.x * 128;
    const int bn = blockIdx.y * 128;
    const int tid = threadIdx.x;
    const int lane = tid & 63;
    const int w = tid >> 6;
    const int wr = w >> 1, wc = w & 1;

    f32x4 acc[4][4];
#pragma unroll
    for (int m = 0; m < 4; m++)
#pragma unroll
        for (int n = 0; n < 4; n++) acc[m][n] = (f32x4){0.f, 0.f, 0.f, 0.f};

    for (int kt = 0; kt < 256; kt += 32) {
        {   // A tile: thread t -> row t>>1, 16 ushorts at (t&1)*16
            int r = tid >> 1, c = (tid & 1) * 16;
            const unsigned short* g = &A[(long)(bm + r) * 256 + kt + c];
            *(us8*)&As[r][c]     = *(const us8*)(g);
            *(us8*)&As[r][c + 8] = *(const us8*)(g + 8);
        }
        {   // B tile: thread t -> col t>>1, 16 contiguous k at (t&1)*16 (row-copy, conflict-free)
            int col = tid >> 1, kh = (tid & 1) * 16;
            const unsigned short* g = &BT[(long)(bn + col) * 256 + kt + kh];
            *(us8*)&Bs[col][kh]     = *(const us8*)(g);
            *(us8*)&Bs[col][kh + 8] = *(const us8*)(g + 8);
        }
        __syncthreads();

        union U { us4 h[2]; short8 s; };
        const int kb = (lane >> 4) * 4;
        short8 af[4], bf[4];
#pragma unroll
        for (int m = 0; m < 4; m++) {
            int r = wr * 64 + m * 16 + (lane & 15);
            U u; u.h[0] = *(const us4*)&As[r][kb]; u.h[1] = *(const us4*)&As[r][kb + 16];
            af[m] = u.s;
        }
#pragma unroll
        for (int n = 0; n < 4; n++) {
            int cl = wc * 64 + n * 16 + (lane & 15);
            U u; u.h[0] = *(const us4*)&Bs[cl][kb]; u.h[1] = *(const us4*)&Bs[cl][kb + 16];
            bf[n] = u.s;
        }
#pragma unroll
        for (int m = 0; m < 4; m++)
#pragma unroll
            for (int n = 0; n < 4; n++)
                acc[m][n] = __builtin_amdgcn_mfma_f32_16x16x32_bf16(af[m], bf[n], acc[m][n], 0, 0, 0);
        __syncthreads();
    }

#pragma unroll
    for (int m = 0; m < 4; m++) {
        int rbase = bm + wr * 64 + m * 16 + (lane >> 4) * 4;
        float ns[4];
        bool in[4];
        if (MODE == 0) {
#pragma unroll
            for (int j = 0; j < 4; j++) {
                int row = rbase + j;
                in[j] = row < NN;
                ns[j] = in[j] ? nS[row] : 0.f;
            }
        }
#pragma unroll
        for (int n = 0; n < 4; n++) {
            int gc = bn + wc * 64 + n * 16 + (lane & 15);
            float bb = (MODE == 0) ? bias[gc] : 0.f;
#pragma unroll
            for (int j = 0; j < 4; j++) {
                int row = rbase + j;
                if (MODE == 0) {
                    if (in[j]) {
                        float v = fmaxf(acc[m][n][j] + bb, 0.f);
                        __builtin_nontemporal_store(v, &outF[(long)row * 256 + gc]);
                        xbn[(long)row * 256 + gc] = f2bf(v * ns[j]);
                    } else {
                        xbn[(long)row * 256 + gc] = 0;
                    }
                } else {
                    outB[(long)row * NOUT + gc] = f2bf(acc[m][n][j]);
                }
            }
        }
    }
}

// ---- layer-2 aggregation (128-wide bf16), XCD-affine 16-col slices ----
// slice working set: 50048*16*2B = 1.6 MB per XCD L2. 16 edge slots (e=lane>>2).
__global__ __launch_bounds__(256) void k_agg2(const int* __restrict__ degI,
                                              const unsigned short* __restrict__ bucket,
                                              const unsigned short* __restrict__ hgb,
                                              const float* __restrict__ nD,
                                              const float* __restrict__ b,
                                              float* __restrict__ h2,
                                              float* __restrict__ h2b) {
    const int sl = blockIdx.x & 7;
    const int node = (blockIdx.x >> 3) * 4 + (threadIdx.x >> 6);
    const int lane = threadIdx.x & 63;
    if (node >= NN) return;
    const int e = lane >> 2;                      // 16 edge slots
    const int cl = sl * 16 + (lane & 3) * 4;      // ushort col base
    const int deg = degI[node];
    const int bidx = (int)bucket[node * BSTR + lane];
    float acc[4] = {0.f, 0.f, 0.f, 0.f};
    int j = 0;
    for (; j + 32 <= deg; j += 32) {              // uniform; 2 loads in flight
        int s0 = __shfl(bidx, j + e, 64);
        int s1 = __shfl(bidx, j + 16 + e, 64);
        us4 v0 = *(const us4*)&hgb[(long)s0 * 128 + cl];
        us4 v1 = *(const us4*)&hgb[(long)s1 * 128 + cl];
#pragma unroll
        for (int k = 0; k < 4; k++) acc[k] += bf2f(v0[k]) + bf2f(v1[k]);
    }
    if (j + 16 <= deg) {
        int s0 = __shfl(bidx, j + e, 64);
        us4 v0 = *(const us4*)&hgb[(long)s0 * 128 + cl];
#pragma unroll
        for (int k = 0; k < 4; k++) acc[k] += bf2f(v0[k]);
        j += 16;
    }
    if (j < deg) {                                // uniform; j<=48, e<=15 -> j+e<=63
        int s0 = __shfl(bidx, j + e, 64);         // shfl at full exec
        if (e < deg - j) {
            us4 v0 = *(const us4*)&hgb[(long)s0 * 128 + cl];
#pragma unroll
            for (int k = 0; k < 4; k++) acc[k] += bf2f(v0[k]);
        }
    }
#pragma unroll
    for (int k = 0; k < 4; k++) acc[k] += __shfl_xor(acc[k], 4, 64);
#pragma unroll
    for (int k = 0; k < 4; k++) acc[k] += __shfl_xor(acc[k], 8, 64);
#pragma unroll
    for (int k = 0; k < 4; k++) acc[k] += __shfl_xor(acc[k], 16, 64);
#pragma unroll
    for (int k = 0; k < 4; k++) acc[k] += __shfl_xor(acc[k], 32, 64);
    if (e == 0) {
        float nd = nD[node];
        f32x4 v;
#pragma unroll
        for (int k = 0; k < 4; k++) v[k] = acc[k] * nd + b[cl + k];
        __builtin_nontemporal_store(v, (f32x4*)&h2[(long)node * 128 + cl]);
        __builtin_nontemporal_store(v, (f32x4*)&h2b[(long)node * 128 + cl]);
    }
}

extern "C" void kernel_launch(void* const* d_in, const int* in_sizes, int n_in,
                              void* d_out, int out_size, void* d_ws, size_t ws_size,
                              hipStream_t stream) {
    const float* feats = (const float*)d_in[0];
    const int*   src   = (const int*)d_in[1];
    const int*   dst   = (const int*)d_in[2];
    const float* W0 = (const float*)d_in[3];
    const float* b0 = (const float*)d_in[4];
    const float* W1 = (const float*)d_in[5];
    const float* b1 = (const float*)d_in[6];
    const float* W2 = (const float*)d_in[7];
    const float* b2 = (const float*)d_in[8];

    float* out = (float*)d_out;
    float* h0  = out;
    float* h1  = out + (long)NN * 256;
    float* h2  = out + 2L * NN * 256;
    float* h2b = out + 2L * NN * 256 + (long)NN * 128;

    char* ws = (char*)d_ws;
    size_t off = 0;
    auto alloc = [&](size_t bytes) { void* p = ws + off; off += (bytes + 255) & ~255UL; return p; };
    unsigned short* xb   = (unsigned short*)alloc((size_t)MPAD * 256 * 2);
    unsigned short* xb2  = (unsigned short*)alloc((size_t)MPAD * 256 * 2);
    unsigned short* aggb = (unsigned short*)alloc((size_t)MPAD * 256 * 2);
    unsigned short* hgb  = (unsigned short*)alloc((size_t)MPAD * 128 * 2);
    unsigned short* W0T = (unsigned short*)alloc(256 * 256 * 2);
    unsigned short* W1T = (unsigned short*)alloc(256 * 256 * 2);
    unsigned short* W2T = (unsigned short*)alloc(128 * 256 * 2);
    int*   zint   = (int*)alloc((size_t)2 * NN * 4);   // degO | degI (one memset)
    int*   degO   = zint;
    int*   degI   = zint + NN;
    float* nS     = (float*)alloc(NN * 4);
    float* nD     = (float*)alloc(NN * 4);
    unsigned short* bucket = (unsigned short*)alloc((size_t)NN * BSTR * 2);

    // one edge pass: degrees + ushort bucket sort, weight transposes riding along
    hipMemsetAsync(zint, 0, (size_t)2 * NN * 4, stream);
    k_degsortW<<<NE / 256 + 640, 256, 0, stream>>>(src, dst, degO, degI, bucket,
                                                   W0, W1, W2, W0T, W1T, W2T);

    // norms + layer-0 input (float4-vectorized)
    k_prep<<<NN / 4, 256, 0, stream>>>(feats, degO, degI, nS, nD, xb);

    // ---- layer 0 ----
    k_aggb<<<8 * (MPAD / 4), 256, 0, stream>>>(degI, bucket, xb, nD, aggb);
    k_gemm<256, 0><<<dim3(MPAD / 128, 2), 256, 0, stream>>>(aggb, W0T, b0, nS, h0, xb2, nullptr);

    // ---- layer 1 ----
    k_aggb<<<8 * (MPAD / 4), 256, 0, stream>>>(degI, bucket, xb2, nD, aggb);
    k_gemm<256, 0><<<dim3(MPAD / 128, 2), 256, 0, stream>>>(aggb, W1T, b1, nS, h1, xb, nullptr);

    // ---- layer 2: transform-first (gather 128-wide) ----
    k_gemm<128, 1><<<dim3(MPAD / 128, 1), 256, 0, stream>>>(xb, W2T, nullptr, nullptr, nullptr, nullptr, hgb);
    k_agg2<<<8 * ((NN + 3) / 4), 256, 0, stream>>>(degI, bucket, hgb, nD, b2, h2, h2b);
}

// Round 12
// 328.109 us; speedup vs baseline: 1.5580x; 1.5580x over previous
//
#include <hip/hip_runtime.h>
#include <hip/hip_bf16.h>

#define NN 50000
#define NE 800000
#define MPAD 50048   // 391 * 128 (GEMM row padding)
#define BSTR 64      // bucket stride (max in-degree headroom; Poisson(16), ~12 sigma)

typedef __attribute__((ext_vector_type(8))) short short8;
typedef __attribute__((ext_vector_type(4))) float f32x4;
typedef __attribute__((ext_vector_type(4))) unsigned short us4;
typedef __attribute__((ext_vector_type(8))) unsigned short us8;

static __device__ __forceinline__ unsigned short f2bf(float f) {
    union { float f; unsigned int u; } v; v.f = f;
    unsigned int u = v.u;
    return (unsigned short)((u + 0x7FFFu + ((u >> 16) & 1u)) >> 16);  // RNE
}
static __device__ __forceinline__ float bf2f(unsigned short h) {
    union { unsigned int u; float f; } v; v.u = ((unsigned int)h) << 16;
    return v.f;
}

// ---- fused: degree-count + bucket counting-sort (blocks 0..3124) + W transposes ----
// NE = 3125*256 exactly; blocks [3125, 3765) handle the 163840 weight elements.
// bucket is USHORT (src ids < 50000 < 2^16).
__global__ void k_degsortW(const int* __restrict__ src, const int* __restrict__ dst,
                           int* __restrict__ degO, int* __restrict__ degI,
                           unsigned short* __restrict__ bucket,
                           const float* __restrict__ W0, const float* __restrict__ W1,
                           const float* __restrict__ W2,
                           unsigned short* __restrict__ W0T, unsigned short* __restrict__ W1T,
                           unsigned short* __restrict__ W2T) {
    int bid = blockIdx.x;
    int t = threadIdx.x;
    if (bid < NE / 256) {
        int e = bid * 256 + t;
        int s = src[e], d = dst[e];
        atomicAdd(&degO[s], 1);
        int p = atomicAdd(&degI[d], 1);
        bucket[d * BSTR + p] = (unsigned short)s;
    } else {
        int i = (bid - NE / 256) * 256 + t;   // 0 .. 163839
        if (i < 65536) {
            int k = i >> 8, c = i & 255;
            W0T[c * 256 + k] = f2bf(W0[i]);
        } else if (i < 131072) {
            int j = i - 65536;
            int k = j >> 8, c = j & 255;
            W1T[c * 256 + k] = f2bf(W1[j]);
        } else {
            int j = i - 131072;
            int k = j >> 7, c = j & 127;
            W2T[c * 256 + k] = f2bf(W2[j]);
        }
    }
}

// ---- prep: norms + layer-0 input cvt, float4-vectorized; 4 rows per block ----
__global__ __launch_bounds__(256) void k_prep(const float* __restrict__ x,
                                              const int* __restrict__ degO,
                                              const int* __restrict__ degI,
                                              float* __restrict__ nS, float* __restrict__ nD,
                                              unsigned short* __restrict__ xb) {
    const int row = blockIdx.x * 4 + (threadIdx.x >> 6);
    const int l = threadIdx.x & 63;
    int o = degO[row];
    float ns = 1.0f / sqrtf((float)(o > 0 ? o : 1));
    if (l == 0) {
        int d = degI[row];
        nS[row] = ns;
        nD[row] = 1.0f / sqrtf((float)(d > 0 ? d : 1));
    }
    f32x4 v = *(const f32x4*)&x[(long)row * 256 + l * 4];
    us4 ob;
#pragma unroll
    for (int k = 0; k < 4; k++) ob[k] = f2bf(v[k] * ns);
    *(us4*)&xb[(long)row * 256 + l * 4] = ob;
}

// ---------------- gather-aggregate (256-wide bf16), in-register edge indices --------
// wave per node (R10 shape: measured optimum). Lane l preloads bucket[node*64+l];
// per-edge src indices via __shfl, ALL at wave-uniform control flow (R8 lesson).
// Quarter-slots (q=lane>>4) x 16 lanes x 32B per edge; 4 us8 loads in flight.
__global__ __launch_bounds__(256) void k_aggb(const int* __restrict__ degI,
                                              const unsigned short* __restrict__ bucket,
                                              const unsigned short* __restrict__ xb,
                                              const float* __restrict__ nD,
                                              unsigned short* __restrict__ aggb) {
    const int node = blockIdx.x * 4 + (threadIdx.x >> 6);
    const int lane = threadIdx.x & 63;
    const int q = lane >> 4;
    const int cl = (lane & 15) * 16;        // ushort col base (covers cl..cl+15)
    if (node >= NN) {
        if (node < MPAD && q == 0) {
            us8 z = {0,0,0,0,0,0,0,0};
            *(us8*)&aggb[(long)node * 256 + cl] = z;
            *(us8*)&aggb[(long)node * 256 + cl + 8] = z;
        }
        return;
    }
    const int deg = degI[node];
    const int bidx = (int)bucket[node * BSTR + lane];   // whole edge list, in-register
    float acc[16];
#pragma unroll
    for (int k = 0; k < 16; k++) acc[k] = 0.f;
    int j = 0;
    for (; j + 8 <= deg; j += 8) {                 // uniform trip count: full exec
        int s0 = __shfl(bidx, j + q, 64);
        int s1 = __shfl(bidx, j + 4 + q, 64);
        const unsigned short* g0 = &xb[(long)s0 * 256 + cl];
        const unsigned short* g1 = &xb[(long)s1 * 256 + cl];
        us8 a0 = *(const us8*)g0;
        us8 a1 = *(const us8*)(g0 + 8);
        us8 b0 = *(const us8*)g1;
        us8 b1 = *(const us8*)(g1 + 8);
#pragma unroll
        for (int k = 0; k < 8; k++) {
            acc[k]     += bf2f(a0[k]) + bf2f(b0[k]);
            acc[8 + k] += bf2f(a1[k]) + bf2f(b1[k]);
        }
    }
    if (j + 4 <= deg) {                            // uniform condition: full exec
        int s0 = __shfl(bidx, j + q, 64);
        const unsigned short* g0 = &xb[(long)s0 * 256 + cl];
        us8 a0 = *(const us8*)g0;
        us8 a1 = *(const us8*)(g0 + 8);
#pragma unroll
        for (int k = 0; k < 8; k++) { acc[k] += bf2f(a0[k]); acc[8 + k] += bf2f(a1[k]); }
        j += 4;
    }
    if (j < deg) {                                 // uniform; j+q <= 63 always
        int s0 = __shfl(bidx, j + q, 64);          // shfl at full exec (R8 fix)
        if (q < deg - j) {                         // divergent: gather only
            const unsigned short* g0 = &xb[(long)s0 * 256 + cl];
            us8 a0 = *(const us8*)g0;
            us8 a1 = *(const us8*)(g0 + 8);
#pragma unroll
            for (int k = 0; k < 8; k++) { acc[k] += bf2f(a0[k]); acc[8 + k] += bf2f(a1[k]); }
        }
    }
#pragma unroll
    for (int k = 0; k < 16; k++) acc[k] += __shfl_xor(acc[k], 16, 64);
#pragma unroll
    for (int k = 0; k < 16; k++) acc[k] += __shfl_xor(acc[k], 32, 64);
    if (q == 0) {
        float nd = nD[node];
        us8 o0, o1;
#pragma unroll
        for (int k = 0; k < 8; k++) {
            o0[k] = f2bf(acc[k] * nd);
            o1[k] = f2bf(acc[8 + k] * nd);
        }
        *(us8*)&aggb[(long)node * 256 + cl] = o0;
        *(us8*)&aggb[(long)node * 256 + cl + 8] = o1;
    }
}

// ---------------- GEMM: A [MPAD][256] bf16, BT [NOUT][256] bf16 (transposed weights) ----
// MODE 0: h = relu(acc + b) -> outF f32 NT-store (row<NN); xbn = f2bf(h*nS) (pad rows -> 0)
// MODE 1: outB = f2bf(acc)  (raw, no bias)
template<int NOUT, int MODE>
__global__ __launch_bounds__(256) void k_gemm(const unsigned short* __restrict__ A,
                                              const unsigned short* __restrict__ BT,
                                              const float* __restrict__ bias,
                                              const float* __restrict__ nS,
                                              float* __restrict__ outF,
                                              unsigned short* __restrict__ xbn,
                                              unsigned short* __restrict__ outB) {
    __shared__ unsigned short As[128][40];
    __shared__ unsigned short Bs[128][36];   // [col][k], staged from BT row-copies
    const int bm = blockIdx.x * 128;
    const int bn = blockIdx.y * 128;
    const int tid = threadIdx.x;
    const int lane = tid & 63;
    const int w = tid >> 6;
    const int wr = w >> 1, wc = w & 1;

    f32x4 acc[4][4];
#pragma unroll
    for (int m = 0; m < 4; m++)
#pragma unroll
        for (int n = 0; n < 4; n++) acc[m][n] = (f32x4){0.f, 0.f, 0.f, 0.f};

    for (int kt = 0; kt < 256; kt += 32) {
        {   // A tile: thread t -> row t>>1, 16 ushorts at (t&1)*16
            int r = tid >> 1, c = (tid & 1) * 16;
            const unsigned short* g = &A[(long)(bm + r) * 256 + kt + c];
            *(us8*)&As[r][c]     = *(const us8*)(g);
            *(us8*)&As[r][c + 8] = *(const us8*)(g + 8);
        }
        {   // B tile: thread t -> col t>>1, 16 contiguous k at (t&1)*16 (row-copy, conflict-free)
            int col = tid >> 1, kh = (tid & 1) * 16;
            const unsigned short* g = &BT[(long)(bn + col) * 256 + kt + kh];
            *(us8*)&Bs[col][kh]     = *(const us8*)(g);
            *(us8*)&Bs[col][kh + 8] = *(const us8*)(g + 8);
        }
        __syncthreads();

        union U { us4 h[2]; short8 s; };
        const int kb = (lane >> 4) * 4;
        short8 af[4], bf[4];
#pragma unroll
        for (int m = 0; m < 4; m++) {
            int r = wr * 64 + m * 16 + (lane & 15);
            U u; u.h[0] = *(const us4*)&As[r][kb]; u.h[1] = *(const us4*)&As[r][kb + 16];
            af[m] = u.s;
        }
#pragma unroll
        for (int n = 0; n < 4; n++) {
            int cl = wc * 64 + n * 16 + (lane & 15);
            U u; u.h[0] = *(const us4*)&Bs[cl][kb]; u.h[1] = *(const us4*)&Bs[cl][kb + 16];
            bf[n] = u.s;
        }
#pragma unroll
        for (int m = 0; m < 4; m++)
#pragma unroll
            for (int n = 0; n < 4; n++)
                acc[m][n] = __builtin_amdgcn_mfma_f32_16x16x32_bf16(af[m], bf[n], acc[m][n], 0, 0, 0);
        __syncthreads();
    }

#pragma unroll
    for (int m = 0; m < 4; m++) {
        int rbase = bm + wr * 64 + m * 16 + (lane >> 4) * 4;
        float ns[4];
        bool in[4];
        if (MODE == 0) {
#pragma unroll
            for (int j = 0; j < 4; j++) {
                int row = rbase + j;
                in[j] = row < NN;
                ns[j] = in[j] ? nS[row] : 0.f;
            }
        }
#pragma unroll
        for (int n = 0; n < 4; n++) {
            int gc = bn + wc * 64 + n * 16 + (lane & 15);
            float bb = (MODE == 0) ? bias[gc] : 0.f;
#pragma unroll
            for (int j = 0; j < 4; j++) {
                int row = rbase + j;
                if (MODE == 0) {
                    if (in[j]) {
                        float v = fmaxf(acc[m][n][j] + bb, 0.f);
                        __builtin_nontemporal_store(v, &outF[(long)row * 256 + gc]);
                        xbn[(long)row * 256 + gc] = f2bf(v * ns[j]);
                    } else {
                        xbn[(long)row * 256 + gc] = 0;
                    }
                } else {
                    outB[(long)row * NOUT + gc] = f2bf(acc[m][n][j]);
                }
            }
        }
    }
}

// ---------------- layer-2 aggregation (128-wide bf16), in-register edge indices ------
__global__ __launch_bounds__(256) void k_agg2(const int* __restrict__ degI,
                                              const unsigned short* __restrict__ bucket,
                                              const unsigned short* __restrict__ hgb,
                                              const float* __restrict__ nD,
                                              const float* __restrict__ b,
                                              float* __restrict__ h2,
                                              float* __restrict__ h2b) {
    const int node = blockIdx.x * 4 + (threadIdx.x >> 6);
    const int lane = threadIdx.x & 63;
    if (node >= NN) return;
    const int q = lane >> 4;                // quarter: edge slot
    const int cl = (lane & 15) * 8;         // ushort col base
    const int deg = degI[node];
    const int bidx = (int)bucket[node * BSTR + lane];
    float acc[8];
#pragma unroll
    for (int k = 0; k < 8; k++) acc[k] = 0.f;
    int j = 0;
    for (; j + 8 <= deg; j += 8) {
        int s0 = __shfl(bidx, j + q, 64);
        int s1 = __shfl(bidx, j + 4 + q, 64);
        us8 vA = *(const us8*)&hgb[(long)s0 * 128 + cl];
        us8 vB = *(const us8*)&hgb[(long)s1 * 128 + cl];
#pragma unroll
        for (int k = 0; k < 8; k++) acc[k] += bf2f(vA[k]) + bf2f(vB[k]);
    }
    if (j + 4 <= deg) {
        int s0 = __shfl(bidx, j + q, 64);
        us8 vA = *(const us8*)&hgb[(long)s0 * 128 + cl];
#pragma unroll
        for (int k = 0; k < 8; k++) acc[k] += bf2f(vA[k]);
        j += 4;
    }
    if (j < deg) {
        int s0 = __shfl(bidx, j + q, 64);   // shfl at full exec (R8 fix)
        if (q < deg - j) {
            us8 vA = *(const us8*)&hgb[(long)s0 * 128 + cl];
#pragma unroll
            for (int k = 0; k < 8; k++) acc[k] += bf2f(vA[k]);
        }
    }
#pragma unroll
    for (int k = 0; k < 8; k++) acc[k] += __shfl_xor(acc[k], 16, 64);
#pragma unroll
    for (int k = 0; k < 8; k++) acc[k] += __shfl_xor(acc[k], 32, 64);
    if (q == 0) {
        float nd = nD[node];
        f32x4 v0, v1;
#pragma unroll
        for (int k = 0; k < 4; k++) v0[k] = acc[k] * nd + b[cl + k];
#pragma unroll
        for (int k = 0; k < 4; k++) v1[k] = acc[4 + k] * nd + b[cl + 4 + k];
        __builtin_nontemporal_store(v0, (f32x4*)&h2[(long)node * 128 + cl]);
        __builtin_nontemporal_store(v1, (f32x4*)&h2[(long)node * 128 + cl + 4]);
        __builtin_nontemporal_store(v0, (f32x4*)&h2b[(long)node * 128 + cl]);
        __builtin_nontemporal_store(v1, (f32x4*)&h2b[(long)node * 128 + cl + 4]);
    }
}

extern "C" void kernel_launch(void* const* d_in, const int* in_sizes, int n_in,
                              void* d_out, int out_size, void* d_ws, size_t ws_size,
                              hipStream_t stream) {
    const float* feats = (const float*)d_in[0];
    const int*   src   = (const int*)d_in[1];
    const int*   dst   = (const int*)d_in[2];
    const float* W0 = (const float*)d_in[3];
    const float* b0 = (const float*)d_in[4];
    const float* W1 = (const float*)d_in[5];
    const float* b1 = (const float*)d_in[6];
    const float* W2 = (const float*)d_in[7];
    const float* b2 = (const float*)d_in[8];

    float* out = (float*)d_out;
    float* h0  = out;
    float* h1  = out + (long)NN * 256;
    float* h2  = out + 2L * NN * 256;
    float* h2b = out + 2L * NN * 256 + (long)NN * 128;

    char* ws = (char*)d_ws;
    size_t off = 0;
    auto alloc = [&](size_t bytes) { void* p = ws + off; off += (bytes + 255) & ~255UL; return p; };
    unsigned short* xb   = (unsigned short*)alloc((size_t)MPAD * 256 * 2);
    unsigned short* xb2  = (unsigned short*)alloc((size_t)MPAD * 256 * 2);
    unsigned short* aggb = (unsigned short*)alloc((size_t)MPAD * 256 * 2);
    unsigned short* hgb  = (unsigned short*)alloc((size_t)MPAD * 128 * 2);
    unsigned short* W0T = (unsigned short*)alloc(256 * 256 * 2);
    unsigned short* W1T = (unsigned short*)alloc(256 * 256 * 2);
    unsigned short* W2T = (unsigned short*)alloc(128 * 256 * 2);
    int*   zint   = (int*)alloc((size_t)2 * NN * 4);   // degO | degI (one memset)
    int*   degO   = zint;
    int*   degI   = zint + NN;
    float* nS     = (float*)alloc(NN * 4);
    float* nD     = (float*)alloc(NN * 4);
    unsigned short* bucket = (unsigned short*)alloc((size_t)NN * BSTR * 2);

    // one edge pass: degrees + ushort bucket sort, weight transposes riding along
    hipMemsetAsync(zint, 0, (size_t)2 * NN * 4, stream);
    k_degsortW<<<NE / 256 + 640, 256, 0, stream>>>(src, dst, degO, degI, bucket,
                                                   W0, W1, W2, W0T, W1T, W2T);

    // norms + layer-0 input (float4-vectorized)
    k_prep<<<NN / 4, 256, 0, stream>>>(feats, degO, degI, nS, nD, xb);

    // ---- layer 0 ----
    k_aggb<<<MPAD / 4, 256, 0, stream>>>(degI, bucket, xb, nD, aggb);
    k_gemm<256, 0><<<dim3(MPAD / 128, 2), 256, 0, stream>>>(aggb, W0T, b0, nS, h0, xb2, nullptr);

    // ---- layer 1 ----
    k_aggb<<<MPAD / 4, 256, 0, stream>>>(degI, bucket, xb2, nD, aggb);
    k_gemm<256, 0><<<dim3(MPAD / 128, 2), 256, 0, stream>>>(aggb, W1T, b1, nS, h1, xb, nullptr);

    // ---- layer 2: transform-first (gather 128-wide) ----
    k_gemm<128, 1><<<dim3(MPAD / 128, 1), 256, 0, stream>>>(xb, W2T, nullptr, nullptr, nullptr, nullptr, hgb);
    k_agg2<<<(NN + 3) / 4, 256, 0, stream>>>(degI, bucket, hgb, nD, b2, h2, h2b);
}

// Round 13
// 327.486 us; speedup vs baseline: 1.5610x; 1.0019x over previous
//
#include <hip/hip_runtime.h>
#include <hip/hip_bf16.h>

#define NN 50000
#define NE 800000
#define MPAD 50048   // 391 * 128 (GEMM row padding)
#define BSTR 64      // bucket stride (max in-degree headroom; Poisson(16), ~12 sigma)

typedef __attribute__((ext_vector_type(8))) short short8;
typedef __attribute__((ext_vector_type(4))) float f32x4;
typedef __attribute__((ext_vector_type(4))) unsigned short us4;
typedef __attribute__((ext_vector_type(8))) unsigned short us8;

static __device__ __forceinline__ unsigned short f2bf(float f) {
    union { float f; unsigned int u; } v; v.f = f;
    unsigned int u = v.u;
    return (unsigned short)((u + 0x7FFFu + ((u >> 16) & 1u)) >> 16);  // RNE
}
static __device__ __forceinline__ float bf2f(unsigned short h) {
    union { unsigned int u; float f; } v; v.u = ((unsigned int)h) << 16;
    return v.f;
}
static __device__ __forceinline__ float degnorm(int d) {
    return rsqrtf((float)(d > 0 ? d : 1));
}

// ---- fused edge pass + ride-alongs ----
// blocks [0, 3125):            degree count + ushort bucket counting-sort (atomic-bound)
// blocks [3125, 3765):         weight transposes (163840 elems)
// blocks [3765, 3765+12500):   feats -> bf16 (UNSCALED; 4 rows/block, f32x4) — BW-bound
//                              work that hides in the atomic blocks' stall slots.
__global__ void k_degsortW(const int* __restrict__ src, const int* __restrict__ dst,
                           int* __restrict__ degO, int* __restrict__ degI,
                           unsigned short* __restrict__ bucket,
                           const float* __restrict__ W0, const float* __restrict__ W1,
                           const float* __restrict__ W2,
                           unsigned short* __restrict__ W0T, unsigned short* __restrict__ W1T,
                           unsigned short* __restrict__ W2T,
                           const float* __restrict__ feats, unsigned short* __restrict__ xb) {
    int bid = blockIdx.x;
    int t = threadIdx.x;
    if (bid < NE / 256) {
        int e = bid * 256 + t;
        int s = src[e], d = dst[e];
        atomicAdd(&degO[s], 1);
        int p = atomicAdd(&degI[d], 1);
        bucket[d * BSTR + p] = (unsigned short)s;
    } else if (bid < NE / 256 + 640) {
        int i = (bid - NE / 256) * 256 + t;   // 0 .. 163839
        if (i < 65536) {
            int k = i >> 8, c = i & 255;
            W0T[c * 256 + k] = f2bf(W0[i]);
        } else if (i < 131072) {
            int j = i - 65536;
            int k = j >> 8, c = j & 255;
            W1T[c * 256 + k] = f2bf(W1[j]);
        } else {
            int j = i - 131072;
            int k = j >> 7, c = j & 127;
            W2T[c * 256 + k] = f2bf(W2[j]);
        }
    } else {
        int row = (bid - (NE / 256 + 640)) * 4 + (t >> 6);
        int l = t & 63;
        f32x4 v = *(const f32x4*)&feats[(long)row * 256 + l * 4];
        us4 ob;
#pragma unroll
        for (int k = 0; k < 4; k++) ob[k] = f2bf(v[k]);
        *(us4*)&xb[(long)row * 256 + l * 4] = ob;
    }
}

// ---------------- gather-aggregate (256-wide bf16), in-register edge indices --------
// wave per node (R10 shape: measured optimum). Lane l preloads bucket[node*64+l];
// per-edge src indices via __shfl, ALL at wave-uniform control flow (R8 lesson).
// SCALE_SRC: multiply each gathered row by rsqrt(degO[src]) (layer 0, unscaled xb).
// nD applied inline from degI (no nD array).
template<bool SCALE_SRC>
__global__ __launch_bounds__(256) void k_aggb(const int* __restrict__ degI,
                                              const int* __restrict__ degO,
                                              const unsigned short* __restrict__ bucket,
                                              const unsigned short* __restrict__ xb,
                                              unsigned short* __restrict__ aggb) {
    const int node = blockIdx.x * 4 + (threadIdx.x >> 6);
    const int lane = threadIdx.x & 63;
    const int q = lane >> 4;
    const int cl = (lane & 15) * 16;        // ushort col base (covers cl..cl+15)
    if (node >= NN) {
        if (node < MPAD && q == 0) {
            us8 z = {0,0,0,0,0,0,0,0};
            *(us8*)&aggb[(long)node * 256 + cl] = z;
            *(us8*)&aggb[(long)node * 256 + cl + 8] = z;
        }
        return;
    }
    const int deg = degI[node];
    const int bidx = (int)bucket[node * BSTR + lane];   // whole edge list, in-register
    float acc[16];
#pragma unroll
    for (int k = 0; k < 16; k++) acc[k] = 0.f;
    int j = 0;
    for (; j + 8 <= deg; j += 8) {                 // uniform trip count: full exec
        int s0 = __shfl(bidx, j + q, 64);
        int s1 = __shfl(bidx, j + 4 + q, 64);
        float ns0 = 1.f, ns1 = 1.f;
        if (SCALE_SRC) { ns0 = degnorm(degO[s0]); ns1 = degnorm(degO[s1]); }
        const unsigned short* g0 = &xb[(long)s0 * 256 + cl];
        const unsigned short* g1 = &xb[(long)s1 * 256 + cl];
        us8 a0 = *(const us8*)g0;
        us8 a1 = *(const us8*)(g0 + 8);
        us8 b0 = *(const us8*)g1;
        us8 b1 = *(const us8*)(g1 + 8);
#pragma unroll
        for (int k = 0; k < 8; k++) {
            if (SCALE_SRC) {
                acc[k]     += bf2f(a0[k]) * ns0 + bf2f(b0[k]) * ns1;
                acc[8 + k] += bf2f(a1[k]) * ns0 + bf2f(b1[k]) * ns1;
            } else {
                acc[k]     += bf2f(a0[k]) + bf2f(b0[k]);
                acc[8 + k] += bf2f(a1[k]) + bf2f(b1[k]);
            }
        }
    }
    if (j + 4 <= deg) {                            // uniform condition: full exec
        int s0 = __shfl(bidx, j + q, 64);
        float ns0 = SCALE_SRC ? degnorm(degO[s0]) : 1.f;
        const unsigned short* g0 = &xb[(long)s0 * 256 + cl];
        us8 a0 = *(const us8*)g0;
        us8 a1 = *(const us8*)(g0 + 8);
#pragma unroll
        for (int k = 0; k < 8; k++) {
            acc[k]     += SCALE_SRC ? bf2f(a0[k]) * ns0 : bf2f(a0[k]);
            acc[8 + k] += SCALE_SRC ? bf2f(a1[k]) * ns0 : bf2f(a1[k]);
        }
        j += 4;
    }
    if (j < deg) {                                 // uniform; j+q <= 63 always
        int s0 = __shfl(bidx, j + q, 64);          // shfl at full exec (R8 fix)
        if (q < deg - j) {                         // divergent: gather only
            float ns0 = SCALE_SRC ? degnorm(degO[s0]) : 1.f;
            const unsigned short* g0 = &xb[(long)s0 * 256 + cl];
            us8 a0 = *(const us8*)g0;
            us8 a1 = *(const us8*)(g0 + 8);
#pragma unroll
            for (int k = 0; k < 8; k++) {
                acc[k]     += SCALE_SRC ? bf2f(a0[k]) * ns0 : bf2f(a0[k]);
                acc[8 + k] += SCALE_SRC ? bf2f(a1[k]) * ns0 : bf2f(a1[k]);
            }
        }
    }
#pragma unroll
    for (int k = 0; k < 16; k++) acc[k] += __shfl_xor(acc[k], 16, 64);
#pragma unroll
    for (int k = 0; k < 16; k++) acc[k] += __shfl_xor(acc[k], 32, 64);
    if (q == 0) {
        float nd = degnorm(deg);
        us8 o0, o1;
#pragma unroll
        for (int k = 0; k < 8; k++) {
            o0[k] = f2bf(acc[k] * nd);
            o1[k] = f2bf(acc[8 + k] * nd);
        }
        *(us8*)&aggb[(long)node * 256 + cl] = o0;
        *(us8*)&aggb[(long)node * 256 + cl + 8] = o1;
    }
}

// ---------------- GEMM: A [MPAD][256] bf16, BT [NOUT][256] bf16 (transposed weights) ----
// MODE 0: h = relu(acc + b) -> outF f32 NT-store (row<NN); xbn = f2bf(h*rsqrt(degO[row]))
// MODE 1: outB = f2bf(acc)  (raw, no bias)
template<int NOUT, int MODE>
__global__ __launch_bounds__(256) void k_gemm(const unsigned short* __restrict__ A,
                                              const unsigned short* __restrict__ BT,
                                              const float* __restrict__ bias,
                                              const int* __restrict__ degO,
                                              float* __restrict__ outF,
                                              unsigned short* __restrict__ xbn,
                                              unsigned short* __restrict__ outB) {
    __shared__ unsigned short As[128][40];
    __shared__ unsigned short Bs[128][36];   // [col][k], staged from BT row-copies
    const int bm = blockIdx.x * 128;
    const int bn = blockIdx.y * 128;
    const int tid = threadIdx.x;
    const int lane = tid & 63;
    const int w = tid >> 6;
    const int wr = w >> 1, wc = w & 1;

    f32x4 acc[4][4];
#pragma unroll
    for (int m = 0; m < 4; m++)
#pragma unroll
        for (int n = 0; n < 4; n++) acc[m][n] = (f32x4){0.f, 0.f, 0.f, 0.f};

    for (int kt = 0; kt < 256; kt += 32) {
        {   // A tile: thread t -> row t>>1, 16 ushorts at (t&1)*16
            int r = tid >> 1, c = (tid & 1) * 16;
            const unsigned short* g = &A[(long)(bm + r) * 256 + kt + c];
            *(us8*)&As[r][c]     = *(const us8*)(g);
            *(us8*)&As[r][c + 8] = *(const us8*)(g + 8);
        }
        {   // B tile: thread t -> col t>>1, 16 contiguous k at (t&1)*16 (row-copy, conflict-free)
            int col = tid >> 1, kh = (tid & 1) * 16;
            const unsigned short* g = &BT[(long)(bn + col) * 256 + kt + kh];
            *(us8*)&Bs[col][kh]     = *(const us8*)(g);
            *(us8*)&Bs[col][kh + 8] = *(const us8*)(g + 8);
        }
        __syncthreads();

        union U { us4 h[2]; short8 s; };
        const int kb = (lane >> 4) * 4;
        short8 af[4], bf[4];
#pragma unroll
        for (int m = 0; m < 4; m++) {
            int r = wr * 64 + m * 16 + (lane & 15);
            U u; u.h[0] = *(const us4*)&As[r][kb]; u.h[1] = *(const us4*)&As[r][kb + 16];
            af[m] = u.s;
        }
#pragma unroll
        for (int n = 0; n < 4; n++) {
            int cl = wc * 64 + n * 16 + (lane & 15);
            U u; u.h[0] = *(const us4*)&Bs[cl][kb]; u.h[1] = *(const us4*)&Bs[cl][kb + 16];
            bf[n] = u.s;
        }
#pragma unroll
        for (int m = 0; m < 4; m++)
#pragma unroll
            for (int n = 0; n < 4; n++)
                acc[m][n] = __builtin_amdgcn_mfma_f32_16x16x32_bf16(af[m], bf[n], acc[m][n], 0, 0, 0);
        __syncthreads();
    }

#pragma unroll
    for (int m = 0; m < 4; m++) {
        int rbase = bm + wr * 64 + m * 16 + (lane >> 4) * 4;
        float ns[4];
        bool in[4];
        if (MODE == 0) {
#pragma unroll
            for (int j = 0; j < 4; j++) {
                int row = rbase + j;
                in[j] = row < NN;
                ns[j] = in[j] ? degnorm(degO[row]) : 0.f;
            }
        }
#pragma unroll
        for (int n = 0; n < 4; n++) {
            int gc = bn + wc * 64 + n * 16 + (lane & 15);
            float bb = (MODE == 0) ? bias[gc] : 0.f;
#pragma unroll
            for (int j = 0; j < 4; j++) {
                int row = rbase + j;
                if (MODE == 0) {
                    if (in[j]) {
                        float v = fmaxf(acc[m][n][j] + bb, 0.f);
                        __builtin_nontemporal_store(v, &outF[(long)row * 256 + gc]);
                        xbn[(long)row * 256 + gc] = f2bf(v * ns[j]);
                    } else {
                        xbn[(long)row * 256 + gc] = 0;
                    }
                } else {
                    outB[(long)row * NOUT + gc] = f2bf(acc[m][n][j]);
                }
            }
        }
    }
}

// ---------------- layer-2 aggregation (128-wide bf16), in-register edge indices ------
__global__ __launch_bounds__(256) void k_agg2(const int* __restrict__ degI,
                                              const unsigned short* __restrict__ bucket,
                                              const unsigned short* __restrict__ hgb,
                                              const float* __restrict__ b,
                                              float* __restrict__ h2,
                                              float* __restrict__ h2b) {
    const int node = blockIdx.x * 4 + (threadIdx.x >> 6);
    const int lane = threadIdx.x & 63;
    if (node >= NN) return;
    const int q = lane >> 4;                // quarter: edge slot
    const int cl = (lane & 15) * 8;         // ushort col base
    const int deg = degI[node];
    const int bidx = (int)bucket[node * BSTR + lane];
    float acc[8];
#pragma unroll
    for (int k = 0; k < 8; k++) acc[k] = 0.f;
    int j = 0;
    for (; j + 8 <= deg; j += 8) {
        int s0 = __shfl(bidx, j + q, 64);
        int s1 = __shfl(bidx, j + 4 + q, 64);
        us8 vA = *(const us8*)&hgb[(long)s0 * 128 + cl];
        us8 vB = *(const us8*)&hgb[(long)s1 * 128 + cl];
#pragma unroll
        for (int k = 0; k < 8; k++) acc[k] += bf2f(vA[k]) + bf2f(vB[k]);
    }
    if (j + 4 <= deg) {
        int s0 = __shfl(bidx, j + q, 64);
        us8 vA = *(const us8*)&hgb[(long)s0 * 128 + cl];
#pragma unroll
        for (int k = 0; k < 8; k++) acc[k] += bf2f(vA[k]);
        j += 4;
    }
    if (j < deg) {
        int s0 = __shfl(bidx, j + q, 64);   // shfl at full exec (R8 fix)
        if (q < deg - j) {
            us8 vA = *(const us8*)&hgb[(long)s0 * 128 + cl];
#pragma unroll
            for (int k = 0; k < 8; k++) acc[k] += bf2f(vA[k]);
        }
    }
#pragma unroll
    for (int k = 0; k < 8; k++) acc[k] += __shfl_xor(acc[k], 16, 64);
#pragma unroll
    for (int k = 0; k < 8; k++) acc[k] += __shfl_xor(acc[k], 32, 64);
    if (q == 0) {
        float nd = degnorm(deg);
        f32x4 v0, v1;
#pragma unroll
        for (int k = 0; k < 4; k++) v0[k] = acc[k] * nd + b[cl + k];
#pragma unroll
        for (int k = 0; k < 4; k++) v1[k] = acc[4 + k] * nd + b[cl + 4 + k];
        __builtin_nontemporal_store(v0, (f32x4*)&h2[(long)node * 128 + cl]);
        __builtin_nontemporal_store(v1, (f32x4*)&h2[(long)node * 128 + cl + 4]);
        __builtin_nontemporal_store(v0, (f32x4*)&h2b[(long)node * 128 + cl]);
        __builtin_nontemporal_store(v1, (f32x4*)&h2b[(long)node * 128 + cl + 4]);
    }
}

extern "C" void kernel_launch(void* const* d_in, const int* in_sizes, int n_in,
                              void* d_out, int out_size, void* d_ws, size_t ws_size,
                              hipStream_t stream) {
    const float* feats = (const float*)d_in[0];
    const int*   src   = (const int*)d_in[1];
    const int*   dst   = (const int*)d_in[2];
    const float* W0 = (const float*)d_in[3];
    const float* b0 = (const float*)d_in[4];
    const float* W1 = (const float*)d_in[5];
    const float* b1 = (const float*)d_in[6];
    const float* W2 = (const float*)d_in[7];
    const float* b2 = (const float*)d_in[8];

    float* out = (float*)d_out;
    float* h0  = out;
    float* h1  = out + (long)NN * 256;
    float* h2  = out + 2L * NN * 256;
    float* h2b = out + 2L * NN * 256 + (long)NN * 128;

    char* ws = (char*)d_ws;
    size_t off = 0;
    auto alloc = [&](size_t bytes) { void* p = ws + off; off += (bytes + 255) & ~255UL; return p; };
    unsigned short* xb   = (unsigned short*)alloc((size_t)MPAD * 256 * 2);
    unsigned short* xb2  = (unsigned short*)alloc((size_t)MPAD * 256 * 2);
    unsigned short* aggb = (unsigned short*)alloc((size_t)MPAD * 256 * 2);
    unsigned short* hgb  = (unsigned short*)alloc((size_t)MPAD * 128 * 2);
    unsigned short* W0T = (unsigned short*)alloc(256 * 256 * 2);
    unsigned short* W1T = (unsigned short*)alloc(256 * 256 * 2);
    unsigned short* W2T = (unsigned short*)alloc(128 * 256 * 2);
    int*   zint   = (int*)alloc((size_t)2 * NN * 4);   // degO | degI (one memset)
    int*   degO   = zint;
    int*   degI   = zint + NN;
    unsigned short* bucket = (unsigned short*)alloc((size_t)NN * BSTR * 2);

    // one fused pass: degrees + ushort bucket sort (atomic-bound), with the
    // weight transposes AND the 51 MB feats->bf16 conversion riding along in
    // the stall slots.
    hipMemsetAsync(zint, 0, (size_t)2 * NN * 4, stream);
    k_degsortW<<<NE / 256 + 640 + NN / 4, 256, 0, stream>>>(
        src, dst, degO, degI, bucket, W0, W1, W2, W0T, W1T, W2T, feats, xb);

    // ---- layer 0 (xb unscaled -> per-src rsqrt(degO) applied in gather) ----
    k_aggb<true><<<MPAD / 4, 256, 0, stream>>>(degI, degO, bucket, xb, aggb);
    k_gemm<256, 0><<<dim3(MPAD / 128, 2), 256, 0, stream>>>(aggb, W0T, b0, degO, h0, xb2, nullptr);

    // ---- layer 1 (xb2 has nS pre-folded by epilogue) ----
    k_aggb<false><<<MPAD / 4, 256, 0, stream>>>(degI, degO, bucket, xb2, aggb);
    k_gemm<256, 0><<<dim3(MPAD / 128, 2), 256, 0, stream>>>(aggb, W1T, b1, degO, h1, xb, nullptr);

    // ---- layer 2: transform-first (gather 128-wide) ----
    k_gemm<128, 1><<<dim3(MPAD / 128, 1), 256, 0, stream>>>(xb, W2T, nullptr, nullptr, nullptr, nullptr, hgb);
    k_agg2<<<(NN + 3) / 4, 256, 0, stream>>>(degI, bucket, hgb, b2, h2, h2b);
}

// Round 14
// 313.796 us; speedup vs baseline: 1.6291x; 1.0436x over previous
//
#include <hip/hip_runtime.h>
#include <hip/hip_bf16.h>

#define NN 50000
#define NE 800000
#define MPAD 50048   // 391 * 128 (GEMM row padding)
#define BSTR 64      // bucket stride (max in-degree headroom; Poisson(16), ~12 sigma)

typedef __attribute__((ext_vector_type(8))) short short8;
typedef __attribute__((ext_vector_type(4))) float f32x4;
typedef __attribute__((ext_vector_type(4))) unsigned short us4;
typedef __attribute__((ext_vector_type(8))) unsigned short us8;

static __device__ __forceinline__ unsigned short f2bf(float f) {
    union { float f; unsigned int u; } v; v.f = f;
    unsigned int u = v.u;
    return (unsigned short)((u + 0x7FFFu + ((u >> 16) & 1u)) >> 16);  // RNE
}
static __device__ __forceinline__ float bf2f(unsigned short h) {
    union { unsigned int u; float f; } v; v.u = ((unsigned int)h) << 16;
    return v.f;
}
static __device__ __forceinline__ float degnorm(int d) {
    return rsqrtf((float)(d > 0 ? d : 1));
}

// ---- fused edge pass, THREAD-level fusion (R13 lesson: block-level ride-alongs
// queue behind the 800k atomic threads; only same-wave work hides in the atomic
// stall window). Each edge thread also converts 16 feats floats (3125 blk x 16
// rows = 50000): the f32x4 loads + f2bf VALU run inside the atomic round-trip.
// blocks [0, 3125): 1 edge/thread (atomics+bucket) + 16 floats feats->bf16
// blocks [3125, 3765): weight transposes (163840 elems)
__global__ void k_degsortW(const int* __restrict__ src, const int* __restrict__ dst,
                           int* __restrict__ degO, int* __restrict__ degI,
                           unsigned short* __restrict__ bucket,
                           const float* __restrict__ W0, const float* __restrict__ W1,
                           const float* __restrict__ W2,
                           unsigned short* __restrict__ W0T, unsigned short* __restrict__ W1T,
                           unsigned short* __restrict__ W2T,
                           const float* __restrict__ feats, unsigned short* __restrict__ xb) {
    int bid = blockIdx.x;
    int t = threadIdx.x;
    if (bid < NE / 256) {
        int e = bid * 256 + t;
        int s = src[e], d = dst[e];
        // independent feats work, issued alongside the atomics
        int row = bid * 16 + (t >> 4);
        int c = (t & 15) * 16;
        const float* fp = &feats[(long)row * 256 + c];
        f32x4 v0 = *(const f32x4*)(fp);
        f32x4 v1 = *(const f32x4*)(fp + 4);
        f32x4 v2 = *(const f32x4*)(fp + 8);
        f32x4 v3 = *(const f32x4*)(fp + 12);
        atomicAdd(&degO[s], 1);
        int p = atomicAdd(&degI[d], 1);
        us4 o0, o1, o2, o3;
#pragma unroll
        for (int k = 0; k < 4; k++) {
            o0[k] = f2bf(v0[k]); o1[k] = f2bf(v1[k]);
            o2[k] = f2bf(v2[k]); o3[k] = f2bf(v3[k]);
        }
        unsigned short* xp = &xb[(long)row * 256 + c];
        *(us4*)(xp)      = o0;
        *(us4*)(xp + 4)  = o1;
        *(us4*)(xp + 8)  = o2;
        *(us4*)(xp + 12) = o3;
        bucket[d * BSTR + p] = (unsigned short)s;
    } else {
        int i = (bid - NE / 256) * 256 + t;   // 0 .. 163839
        if (i < 65536) {
            int k = i >> 8, c = i & 255;
            W0T[c * 256 + k] = f2bf(W0[i]);
        } else if (i < 131072) {
            int j = i - 65536;
            int k = j >> 8, c = j & 255;
            W1T[c * 256 + k] = f2bf(W1[j]);
        } else {
            int j = i - 131072;
            int k = j >> 7, c = j & 127;
            W2T[c * 256 + k] = f2bf(W2[j]);
        }
    }
}

// ---------------- gather-aggregate (256-wide bf16), in-register edge indices --------
// wave per node (R10 shape: measured optimum). Lane l preloads bucket[node*64+l];
// per-edge src indices via __shfl, ALL at wave-uniform control flow (R8 lesson).
// SCALE_SRC: multiply each gathered row by rsqrt(degO[src]) (layer 0, unscaled xb).
template<bool SCALE_SRC>
__global__ __launch_bounds__(256) void k_aggb(const int* __restrict__ degI,
                                              const int* __restrict__ degO,
                                              const unsigned short* __restrict__ bucket,
                                              const unsigned short* __restrict__ xb,
                                              unsigned short* __restrict__ aggb) {
    const int node = blockIdx.x * 4 + (threadIdx.x >> 6);
    const int lane = threadIdx.x & 63;
    const int q = lane >> 4;
    const int cl = (lane & 15) * 16;        // ushort col base (covers cl..cl+15)
    if (node >= NN) {
        if (node < MPAD && q == 0) {
            us8 z = {0,0,0,0,0,0,0,0};
            *(us8*)&aggb[(long)node * 256 + cl] = z;
            *(us8*)&aggb[(long)node * 256 + cl + 8] = z;
        }
        return;
    }
    const int deg = degI[node];
    const int bidx = (int)bucket[node * BSTR + lane];   // whole edge list, in-register
    float acc[16];
#pragma unroll
    for (int k = 0; k < 16; k++) acc[k] = 0.f;
    int j = 0;
    for (; j + 8 <= deg; j += 8) {                 // uniform trip count: full exec
        int s0 = __shfl(bidx, j + q, 64);
        int s1 = __shfl(bidx, j + 4 + q, 64);
        float ns0 = 1.f, ns1 = 1.f;
        if (SCALE_SRC) { ns0 = degnorm(degO[s0]); ns1 = degnorm(degO[s1]); }
        const unsigned short* g0 = &xb[(long)s0 * 256 + cl];
        const unsigned short* g1 = &xb[(long)s1 * 256 + cl];
        us8 a0 = *(const us8*)g0;
        us8 a1 = *(const us8*)(g0 + 8);
        us8 b0 = *(const us8*)g1;
        us8 b1 = *(const us8*)(g1 + 8);
#pragma unroll
        for (int k = 0; k < 8; k++) {
            if (SCALE_SRC) {
                acc[k]     += bf2f(a0[k]) * ns0 + bf2f(b0[k]) * ns1;
                acc[8 + k] += bf2f(a1[k]) * ns0 + bf2f(b1[k]) * ns1;
            } else {
                acc[k]     += bf2f(a0[k]) + bf2f(b0[k]);
                acc[8 + k] += bf2f(a1[k]) + bf2f(b1[k]);
            }
        }
    }
    if (j + 4 <= deg) {                            // uniform condition: full exec
        int s0 = __shfl(bidx, j + q, 64);
        float ns0 = SCALE_SRC ? degnorm(degO[s0]) : 1.f;
        const unsigned short* g0 = &xb[(long)s0 * 256 + cl];
        us8 a0 = *(const us8*)g0;
        us8 a1 = *(const us8*)(g0 + 8);
#pragma unroll
        for (int k = 0; k < 8; k++) {
            acc[k]     += SCALE_SRC ? bf2f(a0[k]) * ns0 : bf2f(a0[k]);
            acc[8 + k] += SCALE_SRC ? bf2f(a1[k]) * ns0 : bf2f(a1[k]);
        }
        j += 4;
    }
    if (j < deg) {                                 // uniform; j+q <= 63 always
        int s0 = __shfl(bidx, j + q, 64);          // shfl at full exec (R8 fix)
        if (q < deg - j) {                         // divergent: gather only
            float ns0 = SCALE_SRC ? degnorm(degO[s0]) : 1.f;
            const unsigned short* g0 = &xb[(long)s0 * 256 + cl];
            us8 a0 = *(const us8*)g0;
            us8 a1 = *(const us8*)(g0 + 8);
#pragma unroll
            for (int k = 0; k < 8; k++) {
                acc[k]     += SCALE_SRC ? bf2f(a0[k]) * ns0 : bf2f(a0[k]);
                acc[8 + k] += SCALE_SRC ? bf2f(a1[k]) * ns0 : bf2f(a1[k]);
            }
        }
    }
#pragma unroll
    for (int k = 0; k < 16; k++) acc[k] += __shfl_xor(acc[k], 16, 64);
#pragma unroll
    for (int k = 0; k < 16; k++) acc[k] += __shfl_xor(acc[k], 32, 64);
    if (q == 0) {
        float nd = degnorm(deg);
        us8 o0, o1;
#pragma unroll
        for (int k = 0; k < 8; k++) {
            o0[k] = f2bf(acc[k] * nd);
            o1[k] = f2bf(acc[8 + k] * nd);
        }
        *(us8*)&aggb[(long)node * 256 + cl] = o0;
        *(us8*)&aggb[(long)node * 256 + cl + 8] = o1;
    }
}

// ---------------- GEMM: A [MPAD][256] bf16, BT [NOUT][256] bf16 (transposed weights) ----
// MODE 0: h = relu(acc + b) -> outF f32 NT-store (row<NN); xbn = f2bf(h*rsqrt(degO[row]))
// MODE 1: outB = f2bf(acc)  (raw, no bias)
template<int NOUT, int MODE>
__global__ __launch_bounds__(256) void k_gemm(const unsigned short* __restrict__ A,
                                              const unsigned short* __restrict__ BT,
                                              const float* __restrict__ bias,
                                              const int* __restrict__ degO,
                                              float* __restrict__ outF,
                                              unsigned short* __restrict__ xbn,
                                              unsigned short* __restrict__ outB) {
    __shared__ unsigned short As[128][40];
    __shared__ unsigned short Bs[128][36];   // [col][k], staged from BT row-copies
    const int bm = blockIdx.x * 128;
    const int bn = blockIdx.y * 128;
    const int tid = threadIdx.x;
    const int lane = tid & 63;
    const int w = tid >> 6;
    const int wr = w >> 1, wc = w & 1;

    f32x4 acc[4][4];
#pragma unroll
    for (int m = 0; m < 4; m++)
#pragma unroll
        for (int n = 0; n < 4; n++) acc[m][n] = (f32x4){0.f, 0.f, 0.f, 0.f};

    for (int kt = 0; kt < 256; kt += 32) {
        {   // A tile: thread t -> row t>>1, 16 ushorts at (t&1)*16
            int r = tid >> 1, c = (tid & 1) * 16;
            const unsigned short* g = &A[(long)(bm + r) * 256 + kt + c];
            *(us8*)&As[r][c]     = *(const us8*)(g);
            *(us8*)&As[r][c + 8] = *(const us8*)(g + 8);
        }
        {   // B tile: thread t -> col t>>1, 16 contiguous k at (t&1)*16 (row-copy, conflict-free)
            int col = tid >> 1, kh = (tid & 1) * 16;
            const unsigned short* g = &BT[(long)(bn + col) * 256 + kt + kh];
            *(us8*)&Bs[col][kh]     = *(const us8*)(g);
            *(us8*)&Bs[col][kh + 8] = *(const us8*)(g + 8);
        }
        __syncthreads();

        union U { us4 h[2]; short8 s; };
        const int kb = (lane >> 4) * 4;
        short8 af[4], bf[4];
#pragma unroll
        for (int m = 0; m < 4; m++) {
            int r = wr * 64 + m * 16 + (lane & 15);
            U u; u.h[0] = *(const us4*)&As[r][kb]; u.h[1] = *(const us4*)&As[r][kb + 16];
            af[m] = u.s;
        }
#pragma unroll
        for (int n = 0; n < 4; n++) {
            int cl = wc * 64 + n * 16 + (lane & 15);
            U u; u.h[0] = *(const us4*)&Bs[cl][kb]; u.h[1] = *(const us4*)&Bs[cl][kb + 16];
            bf[n] = u.s;
        }
#pragma unroll
        for (int m = 0; m < 4; m++)
#pragma unroll
            for (int n = 0; n < 4; n++)
                acc[m][n] = __builtin_amdgcn_mfma_f32_16x16x32_bf16(af[m], bf[n], acc[m][n], 0, 0, 0);
        __syncthreads();
    }

#pragma unroll
    for (int m = 0; m < 4; m++) {
        int rbase = bm + wr * 64 + m * 16 + (lane >> 4) * 4;
        float ns[4];
        bool in[4];
        if (MODE == 0) {
#pragma unroll
            for (int j = 0; j < 4; j++) {
                int row = rbase + j;
                in[j] = row < NN;
                ns[j] = in[j] ? degnorm(degO[row]) : 0.f;
            }
        }
#pragma unroll
        for (int n = 0; n < 4; n++) {
            int gc = bn + wc * 64 + n * 16 + (lane & 15);
            float bb = (MODE == 0) ? bias[gc] : 0.f;
#pragma unroll
            for (int j = 0; j < 4; j++) {
                int row = rbase + j;
                if (MODE == 0) {
                    if (in[j]) {
                        float v = fmaxf(acc[m][n][j] + bb, 0.f);
                        __builtin_nontemporal_store(v, &outF[(long)row * 256 + gc]);
                        xbn[(long)row * 256 + gc] = f2bf(v * ns[j]);
                    } else {
                        xbn[(long)row * 256 + gc] = 0;
                    }
                } else {
                    outB[(long)row * NOUT + gc] = f2bf(acc[m][n][j]);
                }
            }
        }
    }
}

// ---------------- layer-2 aggregation (128-wide bf16), in-register edge indices ------
__global__ __launch_bounds__(256) void k_agg2(const int* __restrict__ degI,
                                              const unsigned short* __restrict__ bucket,
                                              const unsigned short* __restrict__ hgb,
                                              const float* __restrict__ b,
                                              float* __restrict__ h2,
                                              float* __restrict__ h2b) {
    const int node = blockIdx.x * 4 + (threadIdx.x >> 6);
    const int lane = threadIdx.x & 63;
    if (node >= NN) return;
    const int q = lane >> 4;                // quarter: edge slot
    const int cl = (lane & 15) * 8;         // ushort col base
    const int deg = degI[node];
    const int bidx = (int)bucket[node * BSTR + lane];
    float acc[8];
#pragma unroll
    for (int k = 0; k < 8; k++) acc[k] = 0.f;
    int j = 0;
    for (; j + 8 <= deg; j += 8) {
        int s0 = __shfl(bidx, j + q, 64);
        int s1 = __shfl(bidx, j + 4 + q, 64);
        us8 vA = *(const us8*)&hgb[(long)s0 * 128 + cl];
        us8 vB = *(const us8*)&hgb[(long)s1 * 128 + cl];
#pragma unroll
        for (int k = 0; k < 8; k++) acc[k] += bf2f(vA[k]) + bf2f(vB[k]);
    }
    if (j + 4 <= deg) {
        int s0 = __shfl(bidx, j + q, 64);
        us8 vA = *(const us8*)&hgb[(long)s0 * 128 + cl];
#pragma unroll
        for (int k = 0; k < 8; k++) acc[k] += bf2f(vA[k]);
        j += 4;
    }
    if (j < deg) {
        int s0 = __shfl(bidx, j + q, 64);   // shfl at full exec (R8 fix)
        if (q < deg - j) {
            us8 vA = *(const us8*)&hgb[(long)s0 * 128 + cl];
#pragma unroll
            for (int k = 0; k < 8; k++) acc[k] += bf2f(vA[k]);
        }
    }
#pragma unroll
    for (int k = 0; k < 8; k++) acc[k] += __shfl_xor(acc[k], 16, 64);
#pragma unroll
    for (int k = 0; k < 8; k++) acc[k] += __shfl_xor(acc[k], 32, 64);
    if (q == 0) {
        float nd = degnorm(deg);
        f32x4 v0, v1;
#pragma unroll
        for (int k = 0; k < 4; k++) v0[k] = acc[k] * nd + b[cl + k];
#pragma unroll
        for (int k = 0; k < 4; k++) v1[k] = acc[4 + k] * nd + b[cl + 4 + k];
        __builtin_nontemporal_store(v0, (f32x4*)&h2[(long)node * 128 + cl]);
        __builtin_nontemporal_store(v1, (f32x4*)&h2[(long)node * 128 + cl + 4]);
        __builtin_nontemporal_store(v0, (f32x4*)&h2b[(long)node * 128 + cl]);
        __builtin_nontemporal_store(v1, (f32x4*)&h2b[(long)node * 128 + cl + 4]);
    }
}

extern "C" void kernel_launch(void* const* d_in, const int* in_sizes, int n_in,
                              void* d_out, int out_size, void* d_ws, size_t ws_size,
                              hipStream_t stream) {
    const float* feats = (const float*)d_in[0];
    const int*   src   = (const int*)d_in[1];
    const int*   dst   = (const int*)d_in[2];
    const float* W0 = (const float*)d_in[3];
    const float* b0 = (const float*)d_in[4];
    const float* W1 = (const float*)d_in[5];
    const float* b1 = (const float*)d_in[6];
    const float* W2 = (const float*)d_in[7];
    const float* b2 = (const float*)d_in[8];

    float* out = (float*)d_out;
    float* h0  = out;
    float* h1  = out + (long)NN * 256;
    float* h2  = out + 2L * NN * 256;
    float* h2b = out + 2L * NN * 256 + (long)NN * 128;

    char* ws = (char*)d_ws;
    size_t off = 0;
    auto alloc = [&](size_t bytes) { void* p = ws + off; off += (bytes + 255) & ~255UL; return p; };
    unsigned short* xb   = (unsigned short*)alloc((size_t)MPAD * 256 * 2);
    unsigned short* xb2  = (unsigned short*)alloc((size_t)MPAD * 256 * 2);
    unsigned short* aggb = (unsigned short*)alloc((size_t)MPAD * 256 * 2);
    unsigned short* hgb  = (unsigned short*)alloc((size_t)MPAD * 128 * 2);
    unsigned short* W0T = (unsigned short*)alloc(256 * 256 * 2);
    unsigned short* W1T = (unsigned short*)alloc(256 * 256 * 2);
    unsigned short* W2T = (unsigned short*)alloc(128 * 256 * 2);
    int*   zint   = (int*)alloc((size_t)2 * NN * 4);   // degO | degI (one memset)
    int*   degO   = zint;
    int*   degI   = zint + NN;
    unsigned short* bucket = (unsigned short*)alloc((size_t)NN * BSTR * 2);

    // one fused pass: degrees + ushort bucket sort, with feats->bf16 fused at
    // THREAD level (hides in atomic latency) and weight transposes as tail blocks.
    hipMemsetAsync(zint, 0, (size_t)2 * NN * 4, stream);
    k_degsortW<<<NE / 256 + 640, 256, 0, stream>>>(
        src, dst, degO, degI, bucket, W0, W1, W2, W0T, W1T, W2T, feats, xb);

    // ---- layer 0 (xb unscaled -> per-src rsqrt(degO) applied in gather) ----
    k_aggb<true><<<MPAD / 4, 256, 0, stream>>>(degI, degO, bucket, xb, aggb);
    k_gemm<256, 0><<<dim3(MPAD / 128, 2), 256, 0, stream>>>(aggb, W0T, b0, degO, h0, xb2, nullptr);

    // ---- layer 1 (xb2 has nS pre-folded by epilogue) ----
    k_aggb<false><<<MPAD / 4, 256, 0, stream>>>(degI, degO, bucket, xb2, aggb);
    k_gemm<256, 0><<<dim3(MPAD / 128, 2), 256, 0, stream>>>(aggb, W1T, b1, degO, h1, xb, nullptr);

    // ---- layer 2: transform-first (gather 128-wide) ----
    k_gemm<128, 1><<<dim3(MPAD / 128, 1), 256, 0, stream>>>(xb, W2T, nullptr, nullptr, nullptr, nullptr, hgb);
    k_agg2<<<(NN + 3) / 4, 256, 0, stream>>>(degI, bucket, hgb, b2, h2, h2b);
}